// Round 1
// baseline (2653.934 us; speedup 1.0000x reference)
//
#include <hip/hip_runtime.h>
#include <math.h>

#define Bsz  16
#define CIN  64
#define LEN  1024
#define HIDN 1024
#define OUTN 512
#define MTOT (Bsz*LEN)   // 16384

// ---------------- small helpers ----------------

__global__ void copy_vec(const float* __restrict__ s, float* __restrict__ d, int n) {
    int i = blockIdx.x * 256 + threadIdx.x;
    if (i < n) d[i] = s[i];
}

// coeffs: (NOUT, HIDN, 4) row-major. Produce Wt[i][c][o] = coeffs[o][c][i+1] for i=0..2
// and beff[o] += sum_c coeffs[o][c][0]  (the order-0 constant term).
__global__ void prep_coeffs(const float* __restrict__ coeffs, float* __restrict__ Wt,
                            float* __restrict__ beff, int NOUT) {
    __shared__ float tile[32][129];   // [o_local][c_local*4 + i], pad breaks conflicts
    int o0 = blockIdx.x * 32, c0 = blockIdx.y * 32;
    int t = threadIdx.x;
    for (int idx = t; idx < 32 * 128; idx += 256) {
        int row = idx >> 7, col = idx & 127;
        tile[row][col] = coeffs[(size_t)(o0 + row) * (HIDN * 4) + (size_t)c0 * 4 + col];
    }
    __syncthreads();
    int oo = t & 31, ccb = t >> 5;   // ccb in 0..7
    for (int i = 1; i < 4; i++) {
        for (int j = 0; j < 4; j++) {
            int cc = ccb + j * 8;
            Wt[((size_t)((i - 1) * HIDN + c0 + cc)) * NOUT + o0 + oo] = tile[oo][cc * 4 + i];
        }
    }
    if (t < 32) {
        float s = 0.f;
        for (int cc = 0; cc < 32; cc++) s += tile[t][cc * 4];
        atomicAdd(beff + o0 + t, s);
    }
}

// h[m][ho] = sum_c x[b][c][l] * Win[c][ho] + bin[ho];  m = b*LEN + l
__global__ __launch_bounds__(256) void proj_in(const float* __restrict__ x,
                                               const float* __restrict__ Win,
                                               const float* __restrict__ bin,
                                               float* __restrict__ h) {
    __shared__ float xs[CIN][17];
    int t = threadIdx.x;
    int m0 = blockIdx.x * 16;
    int b = m0 >> 10, l0 = m0 & 1023;
    for (int idx = t; idx < CIN * 16; idx += 256) {
        int c = idx >> 4, r = idx & 15;
        xs[c][r] = x[((size_t)b * CIN + c) * LEN + l0 + r];
    }
    __syncthreads();
    float acc[16][4];
#pragma unroll
    for (int r = 0; r < 16; r++)
#pragma unroll
        for (int j = 0; j < 4; j++) acc[r][j] = 0.f;
    for (int c = 0; c < CIN; c++) {
        float w0 = Win[c * HIDN + t];
        float w1 = Win[c * HIDN + t + 256];
        float w2 = Win[c * HIDN + t + 512];
        float w3 = Win[c * HIDN + t + 768];
#pragma unroll
        for (int r = 0; r < 16; r++) {
            float xv = xs[c][r];
            acc[r][0] += xv * w0; acc[r][1] += xv * w1;
            acc[r][2] += xv * w2; acc[r][3] += xv * w3;
        }
    }
    float b0 = bin[t], b1 = bin[t + 256], b2 = bin[t + 512], b3 = bin[t + 768];
    for (int r = 0; r < 16; r++) {
        float* dst = h + (size_t)(m0 + r) * HIDN;
        dst[t]       = acc[r][0] + b0;
        dst[t + 256] = acc[r][1] + b1;
        dst[t + 512] = acc[r][2] + b2;
        dst[t + 768] = acc[r][3] + b3;
    }
}

// Y[m][o] = beff[o] + sum_{i=1..3} sum_c A[m][c]^i * Wt[i-1][c][o]
// BM=BN=64, BK=16, 256 threads, 4x4 per thread. Powers computed on the fly.
__global__ __launch_bounds__(256) void kan_gemm(const float* __restrict__ A,
                                                const float* __restrict__ Wt,
                                                const float* __restrict__ beff,
                                                float* __restrict__ Y, int N) {
    __shared__ float hs[16][65];       // [kk][m_local]
    __shared__ float ws[3][16][64];    // [order][kk][o_local]
    int t = threadIdx.x;
    int m0 = blockIdx.x * 64, o0 = blockIdx.y * 64;
    int tx = t & 15, ty = t >> 4;
    float acc[4][4] = {{0.f, 0.f, 0.f, 0.f}};
    int mrow = t >> 2, cb = (t & 3) * 4;
    for (int c0 = 0; c0 < HIDN; c0 += 16) {
        float4 v = *(const float4*)(A + (size_t)(m0 + mrow) * HIDN + c0 + cb);
        hs[cb + 0][mrow] = v.x; hs[cb + 1][mrow] = v.y;
        hs[cb + 2][mrow] = v.z; hs[cb + 3][mrow] = v.w;
        for (int idx = t; idx < 3 * 16 * 64; idx += 256) {
            int i = idx >> 10;
            int kk = (idx >> 6) & 15, ooo = idx & 63;
            ws[i][kk][ooo] = Wt[((size_t)(i * HIDN + c0 + kk)) * N + o0 + ooo];
        }
        __syncthreads();
#pragma unroll
        for (int kk = 0; kk < 16; kk++) {
            float a0 = hs[kk][ty * 4 + 0], a1 = hs[kk][ty * 4 + 1];
            float a2 = hs[kk][ty * 4 + 2], a3 = hs[kk][ty * 4 + 3];
            float p[3][4];
            p[0][0] = a0; p[0][1] = a1; p[0][2] = a2; p[0][3] = a3;
            p[1][0] = a0 * a0; p[1][1] = a1 * a1; p[1][2] = a2 * a2; p[1][3] = a3 * a3;
            p[2][0] = p[1][0] * a0; p[2][1] = p[1][1] * a1;
            p[2][2] = p[1][2] * a2; p[2][3] = p[1][3] * a3;
#pragma unroll
            for (int i = 0; i < 3; i++) {
                float w0 = ws[i][kk][tx * 4 + 0], w1 = ws[i][kk][tx * 4 + 1];
                float w2 = ws[i][kk][tx * 4 + 2], w3 = ws[i][kk][tx * 4 + 3];
#pragma unroll
                for (int r = 0; r < 4; r++) {
                    acc[r][0] += p[i][r] * w0; acc[r][1] += p[i][r] * w1;
                    acc[r][2] += p[i][r] * w2; acc[r][3] += p[i][r] * w3;
                }
            }
        }
        __syncthreads();
    }
    for (int r = 0; r < 4; r++) {
        size_t base = (size_t)(m0 + ty * 4 + r) * N + o0;
        for (int j = 0; j < 4; j++)
            Y[base + tx * 4 + j] = acc[r][j] + beff[o0 + tx * 4 + j];
    }
}

// In-place LayerNorm(1024) + exact GELU per row.
__global__ void ln_gelu(float* __restrict__ y, const float* __restrict__ g,
                        const float* __restrict__ be) {
    __shared__ float red[4];
    int m = blockIdx.x, t = threadIdx.x;
    float* row = y + (size_t)m * HIDN;
    float v[4];
    float s = 0.f;
#pragma unroll
    for (int j = 0; j < 4; j++) { v[j] = row[t + j * 256]; s += v[j]; }
    for (int off = 32; off > 0; off >>= 1) s += __shfl_down(s, off, 64);
    if ((t & 63) == 0) red[t >> 6] = s;
    __syncthreads();
    float mu = (red[0] + red[1] + red[2] + red[3]) * (1.f / HIDN);
    __syncthreads();
    float ss = 0.f;
#pragma unroll
    for (int j = 0; j < 4; j++) { float d = v[j] - mu; ss += d * d; }
    for (int off = 32; off > 0; off >>= 1) ss += __shfl_down(ss, off, 64);
    if ((t & 63) == 0) red[t >> 6] = ss;
    __syncthreads();
    float rs = rsqrtf((red[0] + red[1] + red[2] + red[3]) * (1.f / HIDN) + 1e-5f);
#pragma unroll
    for (int j = 0; j < 4; j++) {
        int o = t + j * 256;
        float xn = (v[j] - mu) * rs * g[o] + be[o];
        row[o] = xn * 0.5f * (1.f + erff(xn * 0.70710678118654752f));
    }
}

// LayerNorm(512) per row, then mean over L into out via atomics.
__global__ void ln_pool(const float* __restrict__ y2, const float* __restrict__ g,
                        const float* __restrict__ be, float* __restrict__ out) {
    __shared__ float red[4];
    int m = blockIdx.x, t = threadIdx.x;
    const float* row = y2 + (size_t)m * OUTN;
    float v0 = row[t], v1 = row[t + 256];
    float s = v0 + v1;
    for (int off = 32; off > 0; off >>= 1) s += __shfl_down(s, off, 64);
    if ((t & 63) == 0) red[t >> 6] = s;
    __syncthreads();
    float mu = (red[0] + red[1] + red[2] + red[3]) * (1.f / OUTN);
    __syncthreads();
    float d0 = v0 - mu, d1 = v1 - mu;
    float ss = d0 * d0 + d1 * d1;
    for (int off = 32; off > 0; off >>= 1) ss += __shfl_down(ss, off, 64);
    if ((t & 63) == 0) red[t >> 6] = ss;
    __syncthreads();
    float rs = rsqrtf((red[0] + red[1] + red[2] + red[3]) * (1.f / OUTN) + 1e-5f);
    int b = m >> 10;
    float val0 = (d0 * rs * g[t] + be[t]) * (1.f / LEN);
    float val1 = (d1 * rs * g[t + 256] + be[t + 256]) * (1.f / LEN);
    atomicAdd(out + (size_t)b * OUTN + t, val0);
    atomicAdd(out + (size_t)b * OUTN + t + 256, val1);
}

extern "C" void kernel_launch(void* const* d_in, const int* in_sizes, int n_in,
                              void* d_out, int out_size, void* d_ws, size_t ws_size,
                              hipStream_t stream) {
    const float* x       = (const float*)d_in[0];
    const float* Win     = (const float*)d_in[1];
    const float* bin     = (const float*)d_in[2];
    const float* coeffs1 = (const float*)d_in[3];
    const float* bias1   = (const float*)d_in[4];
    const float* g1      = (const float*)d_in[5];
    const float* beta1   = (const float*)d_in[6];
    const float* coeffs2 = (const float*)d_in[7];
    const float* bias2   = (const float*)d_in[8];
    const float* g2      = (const float*)d_in[9];
    const float* beta2   = (const float*)d_in[10];
    float* out = (float*)d_out;

    float* ws  = (float*)d_ws;
    float* h   = ws;                               // MTOT*HIDN
    float* y1  = h   + (size_t)MTOT * HIDN;        // MTOT*HIDN
    float* W1t = y1  + (size_t)MTOT * HIDN;        // 3*HIDN*HIDN
    float* W2t = W1t + (size_t)3 * HIDN * HIDN;    // 3*HIDN*OUTN
    float* b1e = W2t + (size_t)3 * HIDN * OUTN;    // HIDN
    float* b2e = b1e + HIDN;                       // OUTN
    float* y2  = h;   // alias: h is dead after kan_gemm #1

    hipMemsetAsync(d_out, 0, (size_t)out_size * sizeof(float), stream);
    copy_vec<<<4, 256, 0, stream>>>(bias1, b1e, HIDN);
    copy_vec<<<2, 256, 0, stream>>>(bias2, b2e, OUTN);
    prep_coeffs<<<dim3(HIDN / 32, HIDN / 32), 256, 0, stream>>>(coeffs1, W1t, b1e, HIDN);
    prep_coeffs<<<dim3(OUTN / 32, HIDN / 32), 256, 0, stream>>>(coeffs2, W2t, b2e, OUTN);
    proj_in<<<MTOT / 16, 256, 0, stream>>>(x, Win, bin, h);
    kan_gemm<<<dim3(MTOT / 64, HIDN / 64), 256, 0, stream>>>(h, W1t, b1e, y1, HIDN);
    ln_gelu<<<MTOT, 256, 0, stream>>>(y1, g1, beta1);
    kan_gemm<<<dim3(MTOT / 64, OUTN / 64), 256, 0, stream>>>(y1, W2t, b2e, y2, OUTN);
    ln_pool<<<MTOT, 256, 0, stream>>>(y2, g2, beta2, out);
}

// Round 2
// 417.684 us; speedup vs baseline: 6.3539x; 6.3539x over previous
//
#include <hip/hip_runtime.h>
#include <math.h>

#define Bsz  16
#define CIN  64
#define LEN  1024
#define HIDN 1024
#define OUTN 512
#define MTOT (Bsz*LEN)   // 16384
#define KTOT (3*HIDN)    // 3072

typedef __attribute__((ext_vector_type(8))) short bf16x8;
typedef __attribute__((ext_vector_type(4))) float f32x4;

__device__ __forceinline__ unsigned short f2bf(float x) {
    union { float f; unsigned int u; } v; v.f = x;
    unsigned int r = v.u + 0x7fff + ((v.u >> 16) & 1);   // RNE
    return (unsigned short)(r >> 16);
}
__device__ __forceinline__ float bf2f(unsigned short u) {
    union { unsigned int u; float f; } v; v.u = ((unsigned int)u) << 16;
    return v.f;
}
__device__ __forceinline__ void gload_lds16(const void* g, void* l) {
    // width=16 async global->LDS; LDS dest = wave-uniform base + lane*16
    __builtin_amdgcn_global_load_lds((const __attribute__((address_space(1))) void*)g,
                                     (__attribute__((address_space(3))) void*)l, 16, 0, 0);
}

// ---------------- prep: coeffs (NOUT,HIDN,4) -> WT[o][k] bf16 (k = i*HIDN + c, i=1..3)
// and beff[o] = bias[o] + sum_c coeffs[o][c][0]
__global__ __launch_bounds__(256) void prep_w(const float* __restrict__ coeffs,
                                              const float* __restrict__ bias,
                                              unsigned short* __restrict__ WT,
                                              float* __restrict__ beff) {
    int o = blockIdx.x, t = threadIdx.x;
    float s = 0.f;
    unsigned short* wrow = WT + (size_t)o * KTOT;
    for (int c = t; c < HIDN; c += 256) {
        float4 v = *(const float4*)(coeffs + ((size_t)o * HIDN + c) * 4);
        s += v.x;
        wrow[c]            = f2bf(v.y);
        wrow[HIDN + c]     = f2bf(v.z);
        wrow[2 * HIDN + c] = f2bf(v.w);
    }
    __shared__ float red[4];
    for (int off = 32; off > 0; off >>= 1) s += __shfl_down(s, off, 64);
    if ((t & 63) == 0) red[t >> 6] = s;
    __syncthreads();
    if (t == 0) beff[o] = bias[o] + red[0] + red[1] + red[2] + red[3];
}

// ---------------- proj_in: h = x @ Win + bin, emit bf16 powers [h, h^2, h^3]
__global__ __launch_bounds__(256) void proj_in(const float* __restrict__ x,
                                               const float* __restrict__ Win,
                                               const float* __restrict__ bin,
                                               unsigned short* __restrict__ Hpow) {
    __shared__ float xs[CIN][17];
    int t = threadIdx.x;
    int m0 = blockIdx.x * 16;
    int b = m0 >> 10, l0 = m0 & 1023;
    for (int idx = t; idx < CIN * 16; idx += 256) {
        int c = idx >> 4, r = idx & 15;
        xs[c][r] = x[((size_t)b * CIN + c) * LEN + l0 + r];
    }
    __syncthreads();
    float acc[16][4];
#pragma unroll
    for (int r = 0; r < 16; r++)
#pragma unroll
        for (int j = 0; j < 4; j++) acc[r][j] = 0.f;
    for (int c = 0; c < CIN; c++) {
        float w0 = Win[c * HIDN + t];
        float w1 = Win[c * HIDN + t + 256];
        float w2 = Win[c * HIDN + t + 512];
        float w3 = Win[c * HIDN + t + 768];
#pragma unroll
        for (int r = 0; r < 16; r++) {
            float xv = xs[c][r];
            acc[r][0] += xv * w0; acc[r][1] += xv * w1;
            acc[r][2] += xv * w2; acc[r][3] += xv * w3;
        }
    }
    float bb[4] = { bin[t], bin[t + 256], bin[t + 512], bin[t + 768] };
    for (int r = 0; r < 16; r++) {
        unsigned short* dst = Hpow + (size_t)(m0 + r) * KTOT;
#pragma unroll
        for (int j = 0; j < 4; j++) {
            int o = t + j * 256;
            float h = acc[r][j] + bb[j];
            float h2 = h * h, h3 = h2 * h;
            dst[o]            = f2bf(h);
            dst[HIDN + o]     = f2bf(h2);
            dst[2 * HIDN + o] = f2bf(h3);
        }
    }
}

// ---------------- MFMA GEMM: Y[M][N] = A(M x 3072 bf16) @ BT(N x 3072 bf16)^T + beff
// BM=BN=128, BK=64; 256 threads = 4 waves, each computing a 64x64 quadrant.
template<int N, bool BF16OUT>
__global__ __launch_bounds__(256) void mfma_gemm(const unsigned short* __restrict__ A,
                                                 const unsigned short* __restrict__ BT,
                                                 const float* __restrict__ beff,
                                                 void* __restrict__ Yv) {
    __shared__ unsigned short As[128 * 64];   // chunk(r,cc) holds global chunk (r, cc ^ (r&7))
    __shared__ unsigned short Bs[128 * 64];
    int t = threadIdx.x;
    int lane = t & 63, wave = t >> 6;
    int m0 = blockIdx.x * 128, n0 = blockIdx.y * 128;
    const unsigned short* Ab = A + (size_t)m0 * KTOT;
    const unsigned short* Bb = BT + (size_t)n0 * KTOT;

    int srow = lane >> 3;                 // 0..7 within an 8-row staging group
    int sgcc = (lane & 7) ^ srow;         // swizzled global 16B-chunk column

    f32x4 acc[4][4] = {};
    int wr = (wave >> 1) * 64;            // wave's row offset in the 128-tile
    int wc = (wave & 1) * 64;
    int col = lane & 15, quad = lane >> 4;

    for (int k0 = 0; k0 < KTOT; k0 += 64) {
#pragma unroll
        for (int j = 0; j < 4; j++) {
            int rgrp = wave * 32 + j * 8;   // wave-uniform
            gload_lds16(Ab + ((size_t)(rgrp + srow) * KTOT + k0 + sgcc * 8), As + rgrp * 64);
            gload_lds16(Bb + ((size_t)(rgrp + srow) * KTOT + k0 + sgcc * 8), Bs + rgrp * 64);
        }
        __syncthreads();
#pragma unroll
        for (int ks = 0; ks < 2; ks++) {
            int kchunk = ks * 4 + quad;     // 16B chunk index (k = kchunk*8)
            bf16x8 af[4], bf[4];
#pragma unroll
            for (int mt = 0; mt < 4; mt++) {
                int r = wr + mt * 16 + col;
                af[mt] = *(const bf16x8*)(As + r * 64 + ((kchunk ^ (r & 7)) << 3));
            }
#pragma unroll
            for (int nt = 0; nt < 4; nt++) {
                int c = wc + nt * 16 + col;
                bf[nt] = *(const bf16x8*)(Bs + c * 64 + ((kchunk ^ (c & 7)) << 3));
            }
#pragma unroll
            for (int mt = 0; mt < 4; mt++)
#pragma unroll
                for (int nt = 0; nt < 4; nt++)
                    acc[mt][nt] = __builtin_amdgcn_mfma_f32_16x16x32_bf16(af[mt], bf[nt], acc[mt][nt], 0, 0, 0);
        }
        __syncthreads();
    }
    // epilogue: D layout col=lane&15, row=quad*4+reg
#pragma unroll
    for (int nt = 0; nt < 4; nt++) {
        int oc = n0 + wc + nt * 16 + col;
        float bo = beff[oc];
#pragma unroll
        for (int mt = 0; mt < 4; mt++) {
#pragma unroll
            for (int rg = 0; rg < 4; rg++) {
                int mr = m0 + wr + mt * 16 + quad * 4 + rg;
                float v = acc[mt][nt][rg] + bo;
                if (BF16OUT) ((unsigned short*)Yv)[(size_t)mr * N + oc] = f2bf(v);
                else         ((float*)Yv)[(size_t)mr * N + oc] = v;
            }
        }
    }
}

// ---------------- LN(1024) + exact GELU, emit bf16 powers [g, g^2, g^3]
__global__ __launch_bounds__(256) void ln_gelu(const unsigned short* __restrict__ y1,
                                               const float* __restrict__ g,
                                               const float* __restrict__ be,
                                               unsigned short* __restrict__ Gpow) {
    __shared__ float red[4];
    int m = blockIdx.x, t = threadIdx.x;
    const unsigned short* row = y1 + (size_t)m * HIDN;
    float v[4];
    float s = 0.f;
#pragma unroll
    for (int j = 0; j < 4; j++) { v[j] = bf2f(row[t + j * 256]); s += v[j]; }
    for (int off = 32; off > 0; off >>= 1) s += __shfl_down(s, off, 64);
    if ((t & 63) == 0) red[t >> 6] = s;
    __syncthreads();
    float mu = (red[0] + red[1] + red[2] + red[3]) * (1.f / HIDN);
    __syncthreads();
    float ss = 0.f;
#pragma unroll
    for (int j = 0; j < 4; j++) { float d = v[j] - mu; ss += d * d; }
    for (int off = 32; off > 0; off >>= 1) ss += __shfl_down(ss, off, 64);
    if ((t & 63) == 0) red[t >> 6] = ss;
    __syncthreads();
    float rs = rsqrtf((red[0] + red[1] + red[2] + red[3]) * (1.f / HIDN) + 1e-5f);
    unsigned short* dst = Gpow + (size_t)m * KTOT;
#pragma unroll
    for (int j = 0; j < 4; j++) {
        int o = t + j * 256;
        float xn = (v[j] - mu) * rs * g[o] + be[o];
        float gl = xn * 0.5f * (1.f + erff(xn * 0.70710678118654752f));
        float g2 = gl * gl, g3 = g2 * gl;
        dst[o]            = f2bf(gl);
        dst[HIDN + o]     = f2bf(g2);
        dst[2 * HIDN + o] = f2bf(g3);
    }
}

// ---------------- LN(512) per row + mean over L -> out (atomics)
__global__ __launch_bounds__(256) void ln_pool(const float* __restrict__ y2,
                                               const float* __restrict__ g,
                                               const float* __restrict__ be,
                                               float* __restrict__ out) {
    __shared__ float red[4];
    int m = blockIdx.x, t = threadIdx.x;
    const float* row = y2 + (size_t)m * OUTN;
    float v0 = row[t], v1 = row[t + 256];
    float s = v0 + v1;
    for (int off = 32; off > 0; off >>= 1) s += __shfl_down(s, off, 64);
    if ((t & 63) == 0) red[t >> 6] = s;
    __syncthreads();
    float mu = (red[0] + red[1] + red[2] + red[3]) * (1.f / OUTN);
    __syncthreads();
    float d0 = v0 - mu, d1 = v1 - mu;
    float ss = d0 * d0 + d1 * d1;
    for (int off = 32; off > 0; off >>= 1) ss += __shfl_down(ss, off, 64);
    if ((t & 63) == 0) red[t >> 6] = ss;
    __syncthreads();
    float rs = rsqrtf((red[0] + red[1] + red[2] + red[3]) * (1.f / OUTN) + 1e-5f);
    int b = m >> 10;
    float val0 = (d0 * rs * g[t] + be[t]) * (1.f / LEN);
    float val1 = (d1 * rs * g[t + 256] + be[t + 256]) * (1.f / LEN);
    atomicAdd(out + (size_t)b * OUTN + t, val0);
    atomicAdd(out + (size_t)b * OUTN + t + 256, val1);
}

extern "C" void kernel_launch(void* const* d_in, const int* in_sizes, int n_in,
                              void* d_out, int out_size, void* d_ws, size_t ws_size,
                              hipStream_t stream) {
    const float* x       = (const float*)d_in[0];
    const float* Win     = (const float*)d_in[1];
    const float* bin     = (const float*)d_in[2];
    const float* coeffs1 = (const float*)d_in[3];
    const float* bias1   = (const float*)d_in[4];
    const float* g1      = (const float*)d_in[5];
    const float* beta1   = (const float*)d_in[6];
    const float* coeffs2 = (const float*)d_in[7];
    const float* bias2   = (const float*)d_in[8];
    const float* g2      = (const float*)d_in[9];
    const float* beta2   = (const float*)d_in[10];
    float* out = (float*)d_out;

    char* ws = (char*)d_ws;
    // Hpow (bf16, M x 3072) aliases G2pow; y1 (bf16, M x 1024) aliases y2 (f32, M x 512)
    unsigned short* Hpow = (unsigned short*)ws;                         // 100,663,296 B
    char* p1 = ws + (size_t)MTOT * KTOT * 2;
    unsigned short* y1   = (unsigned short*)p1;                         // 33,554,432 B
    float*          y2   = (float*)p1;                                  // alias (same size)
    char* p2 = p1 + (size_t)MTOT * HIDN * 2;
    unsigned short* W1T  = (unsigned short*)p2;                         // 6,291,456 B
    char* p3 = p2 + (size_t)HIDN * KTOT * 2;
    unsigned short* W2T  = (unsigned short*)p3;                         // 3,145,728 B
    char* p4 = p3 + (size_t)OUTN * KTOT * 2;
    float* b1e = (float*)p4;                                            // 4 KB
    float* b2e = (float*)(p4 + HIDN * sizeof(float));                   // 2 KB
    unsigned short* G2pow = Hpow;   // alias: Hpow dead after GEMM1

    hipMemsetAsync(d_out, 0, (size_t)out_size * sizeof(float), stream);
    prep_w<<<HIDN, 256, 0, stream>>>(coeffs1, bias1, W1T, b1e);
    prep_w<<<OUTN, 256, 0, stream>>>(coeffs2, bias2, W2T, b2e);
    proj_in<<<MTOT / 16, 256, 0, stream>>>(x, Win, bin, Hpow);
    mfma_gemm<HIDN, true><<<dim3(MTOT / 128, HIDN / 128), 256, 0, stream>>>(Hpow, W1T, b1e, y1);
    ln_gelu<<<MTOT, 256, 0, stream>>>(y1, g1, beta1, G2pow);
    mfma_gemm<OUTN, false><<<dim3(MTOT / 128, OUTN / 128), 256, 0, stream>>>(G2pow, W2T, b2e, y2);
    ln_pool<<<MTOT, 256, 0, stream>>>(y2, g2, beta2, out);
}